// Round 7
// baseline (158.846 us; speedup 1.0000x reference)
//
#include <hip/hip_runtime.h>
#include <stdint.h>

#define NIN 1024
#define NMID 256
#define NOUT 64
#define BM 64

typedef __attribute__((ext_vector_type(8))) short bf16x8;
typedef __attribute__((ext_vector_type(4))) float fx4;
typedef __attribute__((ext_vector_type(16))) float f32x16;
typedef __attribute__((ext_vector_type(4))) uint32_t u32x4;

union FragU { bf16x8 v; uint32_t u[4]; };

static __device__ __forceinline__ uint32_t cvtpk(float lo, float hi) {
  uint32_t r;
  asm("v_cvt_pk_bf16_f32 %0, %1, %2" : "=v"(r) : "v"(lo), "v"(hi));
  return r;
}

#define VMCNT12() asm volatile("s_waitcnt vmcnt(12)" ::: "memory")
#define VMCNT0()  asm volatile("s_waitcnt vmcnt(0)" ::: "memory")
#define SFENCE()  __builtin_amdgcn_sched_barrier(0)

// ---- kernel 1: W1 -> MFMA-fragment-ready bf16 layout, W2 -> bf16 rowmajor ----
// w1f element addr = (c*4096 + kb*32 + r)*8 + e  where n = c*32+r, k = kb*8+e.
__global__ __launch_bounds__(256) void cvt_weights(
    const float* __restrict__ W1, const float* __restrict__ W2,
    unsigned short* __restrict__ w1f, unsigned short* __restrict__ w2b) {
  int gid = blockIdx.x * 256 + threadIdx.x;
  if (gid < 32768) {                      // 8 c * 128 kb * 32 r
    int r = gid & 31;
    int kb = (gid >> 5) & 127;
    int c = gid >> 12;
    const float* s = W1 + (size_t)(c * 32 + r) * NIN + kb * 8;
    fx4 v0 = *(const fx4*)s;
    fx4 v1 = *(const fx4*)(s + 4);
    u32x4 o = {cvtpk(v0.x, v0.y), cvtpk(v0.z, v0.w),
               cvtpk(v1.x, v1.y), cvtpk(v1.z, v1.w)};
    *(u32x4*)(w1f + (size_t)gid * 8) = o;
  } else {
    int e2 = (gid - 32768) << 2;
    if (e2 < NOUT * NMID) {
      fx4 v = *(const fx4*)(W2 + e2);
      uint2 p; p.x = cvtpk(v.x, v.y); p.y = cvtpk(v.z, v.w);
      *(uint2*)(w2b + e2) = p;
    }
  }
}

// ---- kernel 2: fused MLP, register-pipelined, barrier-free layer 1 ----
// 256 thr = 4 waves (wn = col quarter), BM=64 rows/block, 32 stages of BK=32.
// Per stage: issue A(t+1) (8 x fx4 from HBM) + B(t+1) (4 x bf16x8 from L2)
// -> vmcnt(12) (stage t's loads done, t+1's 12 stay in flight) -> cvt + 8 MFMA.
// Prefetch queue NEVER drains to 0 until the final stage. No LDS / barriers
// in layer 1; LDS only for the 32KB h handoff (one barrier in the kernel).
__global__ __launch_bounds__(256, 2) void livenet_main(
    const float* __restrict__ x,
    const unsigned short* __restrict__ w1f,
    const float* __restrict__ b1,
    const unsigned short* __restrict__ w2b,
    const float* __restrict__ b2,
    float* __restrict__ y) {

  __shared__ __align__(16) char smem[32768];  // h [64 rows][512B] XOR-swizzled

  const int tid = threadIdx.x;
  const int lane = tid & 63;
  const int w = tid >> 6;      // wave 0..3 = wn (col quarter)
  const int wn = w;
  const int l31 = lane & 31;
  const int lh = lane >> 5;    // k-half within fragment
  const int row0 = blockIdx.x * BM;

  f32x16 acc[2][2];
#pragma unroll
  for (int mt = 0; mt < 2; ++mt)
#pragma unroll
    for (int nt = 0; nt < 2; ++nt)
#pragma unroll
      for (int q = 0; q < 16; ++q) acc[mt][nt][q] = 0.f;

  // A bases: lane reads x[row0 + mt*32 + l31][k0 + kq*16 + lh*8 ..+8)
  const char* xr0b = (const char*)(x + (size_t)(row0 + l31) * NIN + lh * 8);
  const char* xr1b = (const char*)(x + (size_t)(row0 + 32 + l31) * NIN + lh * 8);
  // B bases: c = wn*2+nt; byte off for stage t, kq: t*2048 + kq*1024 (+lh*512)
  const char* wb0 = (const char*)(w1f + ((size_t)(wn * 2 + 0) * 4096 + l31) * 8) + lh * 512;
  const char* wb1 = (const char*)(w1f + ((size_t)(wn * 2 + 1) * 4096 + l31) * 8) + lh * 512;

  fx4 aP[8], aQ[8];
  bf16x8 bP[4], bQ[4];

  // AR: 8 fx4; layout [mt0:kq0 lo,hi, kq1 lo,hi, mt1:kq0 lo,hi, kq1 lo,hi]
#define ALOAD(AR, p0, p1, kb)                  \
  { AR[0] = *(const fx4*)((p0) + (kb));        \
    AR[1] = *(const fx4*)((p0) + (kb) + 16);   \
    AR[2] = *(const fx4*)((p0) + (kb) + 64);   \
    AR[3] = *(const fx4*)((p0) + (kb) + 80);   \
    AR[4] = *(const fx4*)((p1) + (kb));        \
    AR[5] = *(const fx4*)((p1) + (kb) + 16);   \
    AR[6] = *(const fx4*)((p1) + (kb) + 64);   \
    AR[7] = *(const fx4*)((p1) + (kb) + 80); }

#define BLOAD(BR, q0, q1, tb)                        \
  { BR[0] = *(const bf16x8*)((q0) + (tb));           \
    BR[1] = *(const bf16x8*)((q0) + (tb) + 1024);    \
    BR[2] = *(const bf16x8*)((q1) + (tb));           \
    BR[3] = *(const bf16x8*)((q1) + (tb) + 1024); }

#define STEP(AR, BR)                                                        \
  { FragU f00, f01, f10, f11;                                               \
    f00.u[0] = cvtpk(AR[0].x, AR[0].y); f00.u[1] = cvtpk(AR[0].z, AR[0].w); \
    f00.u[2] = cvtpk(AR[1].x, AR[1].y); f00.u[3] = cvtpk(AR[1].z, AR[1].w); \
    f01.u[0] = cvtpk(AR[2].x, AR[2].y); f01.u[1] = cvtpk(AR[2].z, AR[2].w); \
    f01.u[2] = cvtpk(AR[3].x, AR[3].y); f01.u[3] = cvtpk(AR[3].z, AR[3].w); \
    f10.u[0] = cvtpk(AR[4].x, AR[4].y); f10.u[1] = cvtpk(AR[4].z, AR[4].w); \
    f10.u[2] = cvtpk(AR[5].x, AR[5].y); f10.u[3] = cvtpk(AR[5].z, AR[5].w); \
    f11.u[0] = cvtpk(AR[6].x, AR[6].y); f11.u[1] = cvtpk(AR[6].z, AR[6].w); \
    f11.u[2] = cvtpk(AR[7].x, AR[7].y); f11.u[3] = cvtpk(AR[7].z, AR[7].w); \
    __builtin_amdgcn_s_setprio(1);                                          \
    acc[0][0] = __builtin_amdgcn_mfma_f32_32x32x16_bf16(f00.v, BR[0], acc[0][0], 0, 0, 0); \
    acc[0][1] = __builtin_amdgcn_mfma_f32_32x32x16_bf16(f00.v, BR[2], acc[0][1], 0, 0, 0); \
    acc[1][0] = __builtin_amdgcn_mfma_f32_32x32x16_bf16(f10.v, BR[0], acc[1][0], 0, 0, 0); \
    acc[1][1] = __builtin_amdgcn_mfma_f32_32x32x16_bf16(f10.v, BR[2], acc[1][1], 0, 0, 0); \
    acc[0][0] = __builtin_amdgcn_mfma_f32_32x32x16_bf16(f01.v, BR[1], acc[0][0], 0, 0, 0); \
    acc[0][1] = __builtin_amdgcn_mfma_f32_32x32x16_bf16(f01.v, BR[3], acc[0][1], 0, 0, 0); \
    acc[1][0] = __builtin_amdgcn_mfma_f32_32x32x16_bf16(f11.v, BR[1], acc[1][0], 0, 0, 0); \
    acc[1][1] = __builtin_amdgcn_mfma_f32_32x32x16_bf16(f11.v, BR[3], acc[1][1], 0, 0, 0); \
    __builtin_amdgcn_s_setprio(0); }

  // prologue: stage 0 in flight (12 loads)
  ALOAD(aP, xr0b, xr1b, 0);
  BLOAD(bP, wb0, wb1, 0);

  for (int it = 0; it < 16; ++it) {
    const char* xa0 = xr0b + it * 256;   // stage t0 = 2*it at byte 0
    const char* xa1 = xr1b + it * 256;
    const char* wa0 = wb0 + it * 4096;
    const char* wa1 = wb1 + it * 4096;

    // stage t0: prefetch t0+1 into Q, consume P
    ALOAD(aQ, xa0, xa1, 128);
    BLOAD(bQ, wa0, wa1, 2048);
    VMCNT12();
    SFENCE();
    STEP(aP, bP);

    // stage t0+1: prefetch t0+2 into P (except last), consume Q
    if (it < 15) {
      ALOAD(aP, xa0, xa1, 256);
      BLOAD(bP, wa0, wa1, 4096);
      VMCNT12();
    } else {
      VMCNT0();
    }
    SFENCE();
    STEP(aQ, bQ);
  }

  // ---- layer-1 epilogue: bias+relu -> h bf16 [64][256] (32-chunk XOR) ----
  float b1v[2];
#pragma unroll
  for (int nt = 0; nt < 2; ++nt) b1v[nt] = b1[wn * 64 + nt * 32 + l31];

#pragma unroll
  for (int mt = 0; mt < 2; ++mt) {
#pragma unroll
    for (int nt = 0; nt < 2; ++nt) {
      int col = wn * 64 + nt * 32 + l31;
#pragma unroll
      for (int rg = 0; rg < 16; ++rg) {
        int row = mt * 32 + (rg & 3) + 8 * (rg >> 2) + 4 * lh;
        float v = acc[mt][nt][rg] + b1v[nt];
        v = v > 0.f ? v : 0.f;
        int j = (col >> 3) ^ (row & 31);
        *(unsigned short*)(smem + row * 512 + (j << 4) + (col & 7) * 2) =
            (unsigned short)cvtpk(v, v);
      }
    }
  }
  __syncthreads();

  // ---- layer 2: y[64][64] = relu(h @ W2^T + b2) ----
  f32x16 acc2;
#pragma unroll
  for (int q = 0; q < 16; ++q) acc2[q] = 0.f;

  const int r2 = (w >> 1) * 32;
  const int c2 = (w & 1) * 32;
  const int arow = r2 + l31;
  const uint32_t arx = (uint32_t)(arow & 31);
  const unsigned short* w2row = w2b + (size_t)(c2 + l31) * NMID + lh * 8;

#pragma unroll
  for (int kk = 0; kk < 16; ++kk) {
    bf16x8 a2 = *(const bf16x8*)(smem + arow * 512 +
                                 ((((uint32_t)(kk * 2 + lh)) ^ arx) << 4));
    bf16x8 bw = *(const bf16x8*)(w2row + kk * 16);
    acc2 = __builtin_amdgcn_mfma_f32_32x32x16_bf16(a2, bw, acc2, 0, 0, 0);
  }

  float bias2 = b2[c2 + l31];
#pragma unroll
  for (int rg = 0; rg < 16; ++rg) {
    int row = r2 + (rg & 3) + 8 * (rg >> 2) + 4 * lh;
    float v = acc2[rg] + bias2;
    v = v > 0.f ? v : 0.f;
    y[(size_t)(row0 + row) * NOUT + c2 + l31] = v;
  }
}

extern "C" void kernel_launch(void* const* d_in, const int* in_sizes, int n_in,
                              void* d_out, int out_size, void* d_ws, size_t ws_size,
                              hipStream_t stream) {
  const float* x  = (const float*)d_in[0];
  const float* W1 = (const float*)d_in[1];
  const float* b1 = (const float*)d_in[2];
  const float* W2 = (const float*)d_in[3];
  const float* b2 = (const float*)d_in[4];
  float* y = (float*)d_out;

  unsigned short* w1f = (unsigned short*)d_ws;            // 512 KB frag-layout
  unsigned short* w2b = w1f + (size_t)NMID * NIN;         // 32 KB rowmajor

  const int batch = in_sizes[0] / NIN;

  hipLaunchKernelGGL(cvt_weights, dim3(144), dim3(256), 0, stream,
                     W1, W2, w1f, w2b);
  hipLaunchKernelGGL(livenet_main, dim3(batch / BM), dim3(256), 0, stream,
                     x, w1f, b1, w2b, b2, y);
}

// Round 8
// 79.610 us; speedup vs baseline: 1.9953x; 1.9953x over previous
//
#include <hip/hip_runtime.h>
#include <stdint.h>

#define NIN 1024
#define NMID 256
#define NOUT 64
#define BM 64
#define BK 32
#define NSTEP 32

typedef __attribute__((ext_vector_type(8))) short bf16x8;
typedef __attribute__((ext_vector_type(4))) float fx4;
typedef __attribute__((ext_vector_type(16))) float f32x16;
typedef __attribute__((ext_vector_type(4))) uint32_t u32x4;

#define XBUF 8192        // one x tile: 64 rows x 128B (fp32), 8-chunk XOR swz

union FragU { bf16x8 v; uint32_t u[4]; };

static __device__ __forceinline__ uint32_t cvtpk(float lo, float hi) {
  uint32_t r;
  asm("v_cvt_pk_bf16_f32 %0, %1, %2" : "=v"(r) : "v"(lo), "v"(hi));
  return r;
}
static __device__ __forceinline__ void gload16(const void* g, void* l) {
  __builtin_amdgcn_global_load_lds(
      (const __attribute__((address_space(1))) uint32_t*)g,
      (__attribute__((address_space(3))) uint32_t*)l, 16, 0, 0);
}

#define VMCNT2() asm volatile("s_waitcnt vmcnt(2)" ::: "memory")
#define SBAR()   __builtin_amdgcn_s_barrier()
#define SFENCE() __builtin_amdgcn_sched_barrier(0)

// ---- kernel 1: W1 -> MFMA-fragment-ready bf16 layout, W2 -> bf16 rowmajor ----
// w1f element addr = (c*4096 + kb*32 + r)*8 + e  where n = c*32+r, k = kb*8+e.
__global__ __launch_bounds__(256) void cvt_weights(
    const float* __restrict__ W1, const float* __restrict__ W2,
    unsigned short* __restrict__ w1f, unsigned short* __restrict__ w2b) {
  int gid = blockIdx.x * 256 + threadIdx.x;
  if (gid < 32768) {                      // 8 c * 128 kb * 32 r
    int r = gid & 31;
    int kb = (gid >> 5) & 127;
    int c = gid >> 12;
    const float* s = W1 + (size_t)(c * 32 + r) * NIN + kb * 8;
    fx4 v0 = *(const fx4*)s;
    fx4 v1 = *(const fx4*)(s + 4);
    u32x4 o = {cvtpk(v0.x, v0.y), cvtpk(v0.z, v0.w),
               cvtpk(v1.x, v1.y), cvtpk(v1.z, v1.w)};
    *(u32x4*)(w1f + (size_t)gid * 8) = o;
  } else {
    int e2 = (gid - 32768) << 2;
    if (e2 < NOUT * NMID) {
      fx4 v = *(const fx4*)(W2 + e2);
      uint2 p; p.x = cvtpk(v.x, v.y); p.y = cvtpk(v.z, v.w);
      *(uint2*)(w2b + e2) = p;
    }
  }
}

// ---- kernel 2: fused MLP; 3-buffer depth-2 DMA pipeline, 16 waves/CU ----
// 256 thr = 4 waves (wn = col quarter), BM=64, BK=32, 32 k-steps.
// Per step: vmcnt(2)+barrier -> B(t) from L2 FIRST -> DMA(t+2) (never waited
// until consumed) -> A ds_read+cvt -> 8 MFMA. Queue >= 2 until the tail.
// Exactly 4 blocks/CU resident (launch_bounds(256,4), LDS 32KB) = zero tail.
__global__ __launch_bounds__(256, 4) void livenet_main(
    const float* __restrict__ x,
    const unsigned short* __restrict__ w1f,
    const float* __restrict__ b1,
    const unsigned short* __restrict__ w2b,
    const float* __restrict__ b2,
    float* __restrict__ y) {

  __shared__ __align__(16) char smem[32768];  // 3 x-bufs (24K); h [64][512B] overlays

  const int tid = threadIdx.x;
  const int lane = tid & 63;
  const int w = tid >> 6;      // wave 0..3 = wn (col quarter)
  const int wn = w;
  const int l31 = lane & 31;
  const int lh = lane >> 5;    // k-half within fragment
  const int row0 = blockIdx.x * BM;

  // x staging: 2 chunks/thread; linear LDS dest, inverse-swizzled global src
  uint32_t xsrc[2], xdst[2];
#pragma unroll
  for (int i = 0; i < 2; ++i) {
    uint32_t o = (uint32_t)(i * 4096 + tid * 16);
    uint32_t r = o >> 7;              // row (128B rows), 0..63
    uint32_t pcn = (o >> 4) & 7u;     // physical 16B chunk
    uint32_t j = pcn ^ (r & 7u);      // logical chunk
    xsrc[i] = (uint32_t)(row0 + (int)r) * NIN + j * 4u;  // float elems
    xdst[i] = o;
  }

#define XSTAGE(b3, k0)                                          \
  { char* xb_ = smem + (b3) * XBUF;                             \
    gload16(x + xsrc[0] + (k0), xb_ + xdst[0]);                 \
    gload16(x + xsrc[1] + (k0), xb_ + xdst[1]); }

  f32x16 acc[2][2];
#pragma unroll
  for (int mt = 0; mt < 2; ++mt)
#pragma unroll
    for (int nt = 0; nt < 2; ++nt)
#pragma unroll
      for (int q = 0; q < 16; ++q) acc[mt][nt][q] = 0.f;

  // B bases: c = wn*2+nt; byte addr = base + t*2048 + kf*1024 (+lh*512 folded)
  const char* wbase0 = (const char*)(w1f + ((size_t)(wn * 2 + 0) * 4096 + l31) * 8) + lh * 512;
  const char* wbase1 = (const char*)(w1f + ((size_t)(wn * 2 + 1) * 4096 + l31) * 8) + lh * 512;

  const uint32_t arx = (uint32_t)(l31 & 7);
  const uint32_t ar0 = (uint32_t)(l31) * 128u;        // mt=0 rows
  const uint32_t ar1 = (uint32_t)(32 + l31) * 128u;   // mt=1 rows

  // prologue: stage tiles 0,1 (4 DMAs outstanding)
  XSTAGE(0, 0);
  XSTAGE(1, BK);

  int b3 = 0;   // t % 3
  for (int t = 0; t < NSTEP; ++t) {
    VMCNT2();          // all but the 2 newest retired => DMA(t) landed
    SBAR();
    SFENCE();

    const char* xb = smem + b3 * XBUF;
    const int tb = t * 2048;

    // B frags FIRST (L2-hot, coalesced 1KB/instr)
    bf16x8 bfr[2][2];
#pragma unroll
    for (int kf = 0; kf < 2; ++kf) {
      bfr[0][kf] = *(const bf16x8*)(wbase0 + tb + kf * 1024);
      bfr[1][kf] = *(const bf16x8*)(wbase1 + tb + kf * 1024);
    }

    // DMA for t+2 (newest in queue; never waited before consumption)
    if (t < NSTEP - 2) {
      int nb = b3 + 2; if (nb >= 3) nb -= 3;
      XSTAGE(nb, (t + 2) * BK);
    }

#pragma unroll
    for (int kf = 0; kf < 2; ++kf) {
      uint32_t j0 = (uint32_t)(kf * 4 + lh * 2);
      fx4 va = *(const fx4*)(xb + ar0 + ((j0 ^ arx) << 4));
      fx4 vb = *(const fx4*)(xb + ar0 + (((j0 + 1) ^ arx) << 4));
      fx4 vc = *(const fx4*)(xb + ar1 + ((j0 ^ arx) << 4));
      fx4 vd = *(const fx4*)(xb + ar1 + (((j0 + 1) ^ arx) << 4));
      FragU f, g;
      f.u[0] = cvtpk(va.x, va.y); f.u[1] = cvtpk(va.z, va.w);
      f.u[2] = cvtpk(vb.x, vb.y); f.u[3] = cvtpk(vb.z, vb.w);
      g.u[0] = cvtpk(vc.x, vc.y); g.u[1] = cvtpk(vc.z, vc.w);
      g.u[2] = cvtpk(vd.x, vd.y); g.u[3] = cvtpk(vd.z, vd.w);
      __builtin_amdgcn_s_setprio(1);
      acc[0][0] = __builtin_amdgcn_mfma_f32_32x32x16_bf16(f.v, bfr[0][kf], acc[0][0], 0, 0, 0);
      acc[0][1] = __builtin_amdgcn_mfma_f32_32x32x16_bf16(f.v, bfr[1][kf], acc[0][1], 0, 0, 0);
      acc[1][0] = __builtin_amdgcn_mfma_f32_32x32x16_bf16(g.v, bfr[0][kf], acc[1][0], 0, 0, 0);
      acc[1][1] = __builtin_amdgcn_mfma_f32_32x32x16_bf16(g.v, bfr[1][kf], acc[1][1], 0, 0, 0);
      __builtin_amdgcn_s_setprio(0);
    }

    ++b3; if (b3 >= 3) b3 -= 3;
  }
  __syncthreads();  // full drain before h overlays the staging buffers

  // ---- layer-1 epilogue: bias+relu -> h bf16 [64][256] (32-chunk XOR) ----
  float b1v[2];
#pragma unroll
  for (int nt = 0; nt < 2; ++nt) b1v[nt] = b1[wn * 64 + nt * 32 + l31];

#pragma unroll
  for (int mt = 0; mt < 2; ++mt) {
#pragma unroll
    for (int nt = 0; nt < 2; ++nt) {
      int col = wn * 64 + nt * 32 + l31;
#pragma unroll
      for (int rg = 0; rg < 16; ++rg) {
        int row = mt * 32 + (rg & 3) + 8 * (rg >> 2) + 4 * lh;
        float v = acc[mt][nt][rg] + b1v[nt];
        v = v > 0.f ? v : 0.f;
        int j = (col >> 3) ^ (row & 31);
        *(unsigned short*)(smem + row * 512 + (j << 4) + (col & 7) * 2) =
            (unsigned short)cvtpk(v, v);
      }
    }
  }
  __syncthreads();

  // ---- layer 2: y[64][64] = relu(h @ W2^T + b2) ----
  f32x16 acc2;
#pragma unroll
  for (int q = 0; q < 16; ++q) acc2[q] = 0.f;

  const int r2 = (w >> 1) * 32;
  const int c2 = (w & 1) * 32;
  const int arow = r2 + l31;
  const uint32_t arx2 = (uint32_t)(arow & 31);
  const unsigned short* w2row = w2b + (size_t)(c2 + l31) * NMID + lh * 8;

#pragma unroll
  for (int kk = 0; kk < 16; ++kk) {
    bf16x8 a2 = *(const bf16x8*)(smem + arow * 512 +
                                 ((((uint32_t)(kk * 2 + lh)) ^ arx2) << 4));
    bf16x8 bw = *(const bf16x8*)(w2row + kk * 16);
    acc2 = __builtin_amdgcn_mfma_f32_32x32x16_bf16(a2, bw, acc2, 0, 0, 0);
  }

  float bias2 = b2[c2 + l31];
#pragma unroll
  for (int rg = 0; rg < 16; ++rg) {
    int row = r2 + (rg & 3) + 8 * (rg >> 2) + 4 * lh;
    float v = acc2[rg] + bias2;
    v = v > 0.f ? v : 0.f;
    y[(size_t)(row0 + row) * NOUT + c2 + l31] = v;
  }
}

extern "C" void kernel_launch(void* const* d_in, const int* in_sizes, int n_in,
                              void* d_out, int out_size, void* d_ws, size_t ws_size,
                              hipStream_t stream) {
  const float* x  = (const float*)d_in[0];
  const float* W1 = (const float*)d_in[1];
  const float* b1 = (const float*)d_in[2];
  const float* W2 = (const float*)d_in[3];
  const float* b2 = (const float*)d_in[4];
  float* y = (float*)d_out;

  unsigned short* w1f = (unsigned short*)d_ws;            // 512 KB frag-layout
  unsigned short* w2b = w1f + (size_t)NMID * NIN;         // 32 KB rowmajor

  const int batch = in_sizes[0] / NIN;

  hipLaunchKernelGGL(cvt_weights, dim3(144), dim3(256), 0, stream,
                     W1, W2, w1f, w2b);
  hipLaunchKernelGGL(livenet_main, dim3(batch / BM), dim3(256), 0, stream,
                     x, w1f, b1, w2b, b2, y);
}